// Round 20
// baseline (34.092 us; speedup 1.0000x reference)
//
#include <hip/hip_runtime.h>

#define T_HOR 5
#define MAXIT 100
#define KGRP  13
#define NGRP  ((MAXIT + KGRP - 1) / KGRP)   // 8
#define EPSC  0.01f

typedef float f2 __attribute__((ext_vector_type(2)));

// One LQR sweep, R12 algebra, both subsystems packed in f2 lanes (.x = sub1,
// .y = sub2). Identities: uka = 0.5du - e*D - 0.1 ; ukb = -uka - 0.2 (exact).
// State trajectory x[] fused across iterations (x[t] += dx_t in fwd pass).
__device__ __forceinline__ float iter_once(
    const float (&e_)[T_HOR], const float (&gp)[T_HOR], const float (&hp)[T_HOR],
    f2 pcp, f2 pcv,
    f2 (&xp)[T_HOR], f2 (&xv)[T_HOR],
    f2 (&ua)[T_HOR], f2 (&ub)[T_HOR])
{
    // backward pass: uka = u_a + k_a, ukb = u_b + k_b
    f2 uka[T_HOR], ukb[T_HOR];
    f2 vp = {0.f, 0.f}, vv = {0.f, 0.f};
    #pragma unroll
    for (int t = T_HOR-1; t >= 0; --t) {
        f2 du = ua[t] - ub[t];
        f2 D  = 0.1f*du + vv;
        f2 m  = e_[t]*D;
        f2 ka = (0.5f*du - m) - 0.1f;
        uka[t] = ka;
        ukb[t] = -ka - 0.2f;
        f2 qxp = (pcp + xp[t]) + vp;
        f2 qxv = (pcv + 0.1f*xv[t]) + 0.1f*vp + 0.75f*vv;
        vp = qxp - gp[t]*D;
        vv = qxv - hp[t]*D;
    }

    // forward pass with clip; u and x updated in place
    float dmax1 = 0.f, dmax2 = 0.f;
    f2 dp = {0.f, 0.f}, dv = {0.f, 0.f};
    #pragma unroll
    for (int t = 0; t < T_HOR; ++t) {
        f2 phi = gp[t]*dp + hp[t]*dv;
        f2 ra = uka[t] - phi;
        f2 rb = ukb[t] + phi;
        f2 na, nb;
        na.x = __builtin_amdgcn_fmed3f(ra.x, 0.f, 1.f);
        na.y = __builtin_amdgcn_fmed3f(ra.y, 0.f, 1.f);
        nb.x = __builtin_amdgcn_fmed3f(rb.x, 0.f, 1.f);
        nb.y = __builtin_amdgcn_fmed3f(rb.y, 0.f, 1.f);
        f2 dua = na - ua[t];
        f2 dub = nb - ub[t];
        dmax1 = fmaxf(dmax1, fmaxf(fabsf(dua.x), fabsf(dua.y)));
        dmax2 = fmaxf(dmax2, fmaxf(fabsf(dub.x), fabsf(dub.y)));
        xp[t] += dp; xv[t] += dv;
        f2 ndp = dp + 0.1f*dv;
        f2 ndv = 0.75f*dv + 0.5f*(dua - dub);
        dp = ndp; dv = ndv;
        ua[t] = na; ub[t] = nb;
    }
    return fmaxf(dmax1, dmax2);
}

// R19 structure verbatim; ONLY change: KGRP 3 -> 13 (n*=39 confirmed; groups
// 1-13 / 14-26 / 27-39 put the stop on a group boundary -> j0==gl-1 ->
// no-replay branch fires; 39 iters + 3 barriers instead of 13).
__global__ __launch_bounds__(256)
void mpc_iter_kernel(const float4* __restrict__ x_init,
                     const float4* __restrict__ xd,
                     float4* __restrict__ out,
                     int* __restrict__ gmask,
                     int* __restrict__ cnt)
{
    const int b = blockIdx.x * 256 + threadIdx.x;

    const float4 xi  = x_init[b];   // [p1, p2, v1, v2]
    const float4 xdv = xd[b];
    const float SQ01 = 0.31622776601683794f;
    f2 pcp = {-xdv.x, -xdv.y};
    f2 pcv = {-SQ01*xdv.z, -SQ01*xdv.w};

    // Batch-independent Riccati schedule (constant-folds at compile time)
    float e_[T_HOR], gp[T_HOR], hp[T_HOR];
    {
        float Vpp = 0.f, Vpv = 0.f, Vvv = 0.f;
        #pragma unroll
        for (int t = T_HOR-1; t >= 0; --t) {
            float s  = 0.25f * Vvv;
            float tw = 0.1f + 2.f*s;
            float inv = 1.f / tw;
            e_[t] = 0.5f * inv;
            float g = 0.5f * Vpv;
            float h = 0.05f * Vpv + 0.375f * Vvv;
            gp[t] = g * inv;
            hp[t] = h * inv;
            float nVpp = 1.0f + Vpp - 2.f*g*gp[t];
            float nVpv = 0.1f*Vpp + 0.75f*Vpv - 2.f*g*hp[t];
            float nVvv = 0.1f + 0.01f*Vpp + 0.15f*Vpv + 0.5625f*Vvv - 2.f*h*hp[t];
            Vpp = nVpp; Vpv = nVpv; Vvv = nVvv;
        }
    }

    // u = 0; x = rollout(x_init, u=0) once
    f2 z = {0.f, 0.f};
    f2 ua[T_HOR], ub[T_HOR], xp[T_HOR], xv[T_HOR];
    #pragma unroll
    for (int t = 0; t < T_HOR; ++t) { ua[t] = z; ub[t] = z; }
    xp[0] = f2{xi.x, xi.y};
    xv[0] = f2{xi.z, xi.w};
    #pragma unroll
    for (int t = 0; t < T_HOR-1; ++t) {
        xp[t+1] = xp[t] + 0.1f*xv[t];
        xv[t+1] = 0.75f*xv[t];
    }

    int it_base = 0;
    for (int g = 0; g < NGRP; ++g) {
        // checkpoint controls AND state trajectory at group start
        f2 cka[T_HOR], ckb[T_HOR], ckp[T_HOR], ckv[T_HOR];
        #pragma unroll
        for (int t = 0; t < T_HOR; ++t) {
            cka[t] = ua[t]; ckb[t] = ub[t]; ckp[t] = xp[t]; ckv[t] = xv[t];
        }

        const int gl = (MAXIT - it_base < KGRP) ? (MAXIT - it_base) : KGRP;
        unsigned mask = 0;
        for (int j = 0; j < gl; ++j) {
            float delta = iter_once(e_, gp, hp, pcp, pcv, xp, xv, ua, ub);
            mask |= (delta > EPSC ? 1u : 0u) << j;
        }

        int m = __syncthreads_or((int)mask);
        // ---- software grid barrier g (one-shot counters, memset-reset per replay)
        if (threadIdx.x == 0) {
            if (m) __hip_atomic_fetch_or(&gmask[g], m, __ATOMIC_RELEASE, __HIP_MEMORY_SCOPE_AGENT);
            __hip_atomic_fetch_add(&cnt[g], 1, __ATOMIC_ACQ_REL, __HIP_MEMORY_SCOPE_AGENT);
            while (__hip_atomic_load(&cnt[g], __ATOMIC_ACQUIRE, __HIP_MEMORY_SCOPE_AGENT) < (int)gridDim.x) {
                __builtin_amdgcn_s_sleep(2);
            }
        }
        __syncthreads();
        int gm = __hip_atomic_load(&gmask[g], __ATOMIC_ACQUIRE, __HIP_MEMORY_SCOPE_AGENT);

        // first iteration (0-based within group) where ALL elements had delta<=EPS
        int j0 = __ffs(~(unsigned)gm) - 1;   // bits >= gl are 0 in gm, so j0<=gl
        if (j0 < gl) {
            if (j0 != gl - 1) {
                // stop fired mid-group: restore u,x + replay j0+1 iterations
                #pragma unroll
                for (int t = 0; t < T_HOR; ++t) {
                    ua[t] = cka[t]; ub[t] = ckb[t]; xp[t] = ckp[t]; xv[t] = ckv[t];
                }
                for (int j = 0; j <= j0; ++j) {
                    iter_once(e_, gp, hp, pcp, pcv, xp, xv, ua, ub);
                }
            }
            // else: stop on the group's LAST iteration -> registers already hold
            // u(n*) (replay from checkpoint would recompute the identical values)
            break;
        }
        it_base += KGRP;
        if (it_base >= MAXIT) break;   // hit iteration cap: output u(MAXIT)
    }

    out[b] = make_float4(ua[0].x, ub[0].x, ua[0].y, ub[0].y);
}

extern "C" void kernel_launch(void* const* d_in, const int* in_sizes, int n_in,
                              void* d_out, int out_size, void* d_ws, size_t ws_size,
                              hipStream_t stream) {
    const float4* x_init = (const float4*)d_in[0];
    const float4* xd     = (const float4*)d_in[1];
    float4* out          = (float4*)d_out;
    int* gmask           = (int*)d_ws;
    int* cnt             = (int*)d_ws + NGRP;

    const int B = in_sizes[0] / 4;          // 65536
    hipMemsetAsync(d_ws, 0, 2 * NGRP * sizeof(int), stream);

    dim3 grid(B / 256), block(256);         // 256 blocks = 4 waves/CU, fully resident
    mpc_iter_kernel<<<grid, block, 0, stream>>>(x_init, xd, out, gmask, cnt);
}

// Round 21
// 30.903 us; speedup vs baseline: 1.1032x; 1.1032x over previous
//
#include <hip/hip_runtime.h>

#define T_HOR 5
#define MAXIT 100
#define KGRP  3
#define NGRP  ((MAXIT + KGRP - 1) / KGRP)   // 34
#define EPSC  0.01f

typedef float f2 __attribute__((ext_vector_type(2)));

// One LQR sweep, R12 algebra, both subsystems packed in f2 lanes (.x = sub1,
// .y = sub2). Identities: uka = 0.5du - e*D - 0.1 ; ukb = -uka - 0.2 (exact).
// State trajectory x[] fused across iterations (x[t] += dx_t in fwd pass).
__device__ __forceinline__ float iter_once(
    const float (&e_)[T_HOR], const float (&gp)[T_HOR], const float (&hp)[T_HOR],
    f2 pcp, f2 pcv,
    f2 (&xp)[T_HOR], f2 (&xv)[T_HOR],
    f2 (&ua)[T_HOR], f2 (&ub)[T_HOR])
{
    // backward pass: uka = u_a + k_a, ukb = u_b + k_b
    f2 uka[T_HOR], ukb[T_HOR];
    f2 vp = {0.f, 0.f}, vv = {0.f, 0.f};
    #pragma unroll
    for (int t = T_HOR-1; t >= 0; --t) {
        f2 du = ua[t] - ub[t];
        f2 D  = 0.1f*du + vv;
        f2 m  = e_[t]*D;
        f2 ka = (0.5f*du - m) - 0.1f;
        uka[t] = ka;
        ukb[t] = -ka - 0.2f;
        f2 qxp = (pcp + xp[t]) + vp;
        f2 qxv = (pcv + 0.1f*xv[t]) + 0.1f*vp + 0.75f*vv;
        vp = qxp - gp[t]*D;
        vv = qxv - hp[t]*D;
    }

    // forward pass with clip; u and x updated in place
    float dmax1 = 0.f, dmax2 = 0.f;
    f2 dp = {0.f, 0.f}, dv = {0.f, 0.f};
    #pragma unroll
    for (int t = 0; t < T_HOR; ++t) {
        f2 phi = gp[t]*dp + hp[t]*dv;
        f2 ra = uka[t] - phi;
        f2 rb = ukb[t] + phi;
        f2 na, nb;
        na.x = __builtin_amdgcn_fmed3f(ra.x, 0.f, 1.f);
        na.y = __builtin_amdgcn_fmed3f(ra.y, 0.f, 1.f);
        nb.x = __builtin_amdgcn_fmed3f(rb.x, 0.f, 1.f);
        nb.y = __builtin_amdgcn_fmed3f(rb.y, 0.f, 1.f);
        f2 dua = na - ua[t];
        f2 dub = nb - ub[t];
        dmax1 = fmaxf(dmax1, fmaxf(fabsf(dua.x), fabsf(dua.y)));
        dmax2 = fmaxf(dmax2, fmaxf(fabsf(dub.x), fabsf(dub.y)));
        xp[t] += dp; xv[t] += dv;
        f2 ndp = dp + 0.1f*dv;
        f2 ndv = 0.75f*dv + 0.5f*(dua - dub);
        dp = ndp; dv = ndv;
        ua[t] = na; ub[t] = nb;
    }
    return fmaxf(dmax1, dmax2);
}

// CHAMPION (R19 verbatim): KGRP=3 group loop, checkpoint(u,x)+replay,
// software grid barrier (one-shot counters, memset-reset per replay).
// n*=39 (proved by R19's stop mask) lands on a group boundary -> the
// no-replay branch fires: exactly 39 executed iterations, the minimum
// needed to reproduce the reference's global stopping rule.
__global__ __launch_bounds__(256)
void mpc_iter_kernel(const float4* __restrict__ x_init,
                     const float4* __restrict__ xd,
                     float4* __restrict__ out,
                     int* __restrict__ gmask,
                     int* __restrict__ cnt)
{
    const int b = blockIdx.x * 256 + threadIdx.x;

    const float4 xi  = x_init[b];   // [p1, p2, v1, v2]
    const float4 xdv = xd[b];
    const float SQ01 = 0.31622776601683794f;
    f2 pcp = {-xdv.x, -xdv.y};
    f2 pcv = {-SQ01*xdv.z, -SQ01*xdv.w};

    // Batch-independent Riccati schedule (constant-folds at compile time)
    float e_[T_HOR], gp[T_HOR], hp[T_HOR];
    {
        float Vpp = 0.f, Vpv = 0.f, Vvv = 0.f;
        #pragma unroll
        for (int t = T_HOR-1; t >= 0; --t) {
            float s  = 0.25f * Vvv;
            float tw = 0.1f + 2.f*s;
            float inv = 1.f / tw;
            e_[t] = 0.5f * inv;
            float g = 0.5f * Vpv;
            float h = 0.05f * Vpv + 0.375f * Vvv;
            gp[t] = g * inv;
            hp[t] = h * inv;
            float nVpp = 1.0f + Vpp - 2.f*g*gp[t];
            float nVpv = 0.1f*Vpp + 0.75f*Vpv - 2.f*g*hp[t];
            float nVvv = 0.1f + 0.01f*Vpp + 0.15f*Vpv + 0.5625f*Vvv - 2.f*h*hp[t];
            Vpp = nVpp; Vpv = nVpv; Vvv = nVvv;
        }
    }

    // u = 0; x = rollout(x_init, u=0) once
    f2 z = {0.f, 0.f};
    f2 ua[T_HOR], ub[T_HOR], xp[T_HOR], xv[T_HOR];
    #pragma unroll
    for (int t = 0; t < T_HOR; ++t) { ua[t] = z; ub[t] = z; }
    xp[0] = f2{xi.x, xi.y};
    xv[0] = f2{xi.z, xi.w};
    #pragma unroll
    for (int t = 0; t < T_HOR-1; ++t) {
        xp[t+1] = xp[t] + 0.1f*xv[t];
        xv[t+1] = 0.75f*xv[t];
    }

    int it_base = 0;
    for (int g = 0; g < NGRP; ++g) {
        // checkpoint controls AND state trajectory at group start
        f2 cka[T_HOR], ckb[T_HOR], ckp[T_HOR], ckv[T_HOR];
        #pragma unroll
        for (int t = 0; t < T_HOR; ++t) {
            cka[t] = ua[t]; ckb[t] = ub[t]; ckp[t] = xp[t]; ckv[t] = xv[t];
        }

        const int gl = (MAXIT - it_base < KGRP) ? (MAXIT - it_base) : KGRP;
        unsigned mask = 0;
        for (int j = 0; j < gl; ++j) {
            float delta = iter_once(e_, gp, hp, pcp, pcv, xp, xv, ua, ub);
            mask |= (delta > EPSC ? 1u : 0u) << j;
        }

        int m = __syncthreads_or((int)mask);
        // ---- software grid barrier g (one-shot counters, memset-reset per replay)
        if (threadIdx.x == 0) {
            if (m) __hip_atomic_fetch_or(&gmask[g], m, __ATOMIC_RELEASE, __HIP_MEMORY_SCOPE_AGENT);
            __hip_atomic_fetch_add(&cnt[g], 1, __ATOMIC_ACQ_REL, __HIP_MEMORY_SCOPE_AGENT);
            while (__hip_atomic_load(&cnt[g], __ATOMIC_ACQUIRE, __HIP_MEMORY_SCOPE_AGENT) < (int)gridDim.x) {
                __builtin_amdgcn_s_sleep(2);
            }
        }
        __syncthreads();
        int gm = __hip_atomic_load(&gmask[g], __ATOMIC_ACQUIRE, __HIP_MEMORY_SCOPE_AGENT);

        // first iteration (0-based within group) where ALL elements had delta<=EPS
        int j0 = __ffs(~(unsigned)gm) - 1;   // bits >= gl are 0 in gm, so j0<=gl
        if (j0 < gl) {
            if (j0 != gl - 1) {
                // stop fired mid-group: restore u,x + replay j0+1 iterations
                #pragma unroll
                for (int t = 0; t < T_HOR; ++t) {
                    ua[t] = cka[t]; ub[t] = ckb[t]; xp[t] = ckp[t]; xv[t] = ckv[t];
                }
                for (int j = 0; j <= j0; ++j) {
                    iter_once(e_, gp, hp, pcp, pcv, xp, xv, ua, ub);
                }
            }
            // else: stop on the group's LAST iteration -> registers already hold
            // u(n*) (replay from checkpoint would recompute the identical values)
            break;
        }
        it_base += KGRP;
        if (it_base >= MAXIT) break;   // hit iteration cap: output u(MAXIT)
    }

    out[b] = make_float4(ua[0].x, ub[0].x, ua[0].y, ub[0].y);
}

extern "C" void kernel_launch(void* const* d_in, const int* in_sizes, int n_in,
                              void* d_out, int out_size, void* d_ws, size_t ws_size,
                              hipStream_t stream) {
    const float4* x_init = (const float4*)d_in[0];
    const float4* xd     = (const float4*)d_in[1];
    float4* out          = (float4*)d_out;
    int* gmask           = (int*)d_ws;
    int* cnt             = (int*)d_ws + NGRP;

    const int B = in_sizes[0] / 4;          // 65536
    // REQUIRED: recovers cnt/gmask from the harness's 0xAA poison; the spin
    // barrier would deadlock on poisoned counters. ~1.5 us, not removable.
    hipMemsetAsync(d_ws, 0, 2 * NGRP * sizeof(int), stream);

    dim3 grid(B / 256), block(256);         // 256 blocks = 4 waves/CU, fully resident
    mpc_iter_kernel<<<grid, block, 0, stream>>>(x_init, xd, out, gmask, cnt);
}